// Round 3
// baseline (4083.934 us; speedup 1.0000x reference)
//
#include <hip/hip_runtime.h>
#include <hip/hip_bf16.h>

typedef __hip_bfloat16 bf16;

#define T_  5
#define H_  64
#define W_  96
#define HW_ (H_*W_)
#define C_  256
#define NH_ 8
#define DH_ 32
#define NL_ 5
#define NP_ 4
#define LQ_ (T_*HW_)

static __device__ __forceinline__ float tof(float v){ return v; }
static __device__ __forceinline__ float tof(bf16 v){ return __bfloat162float(v); }

// ---------------------------------------------------------------- flow init
__global__ __launch_bounds__(256) void flow_init_k(const float* __restrict__ ff,
                                                   const float* __restrict__ fb,
                                                   float* __restrict__ flows){
  int i = blockIdx.x*256 + threadIdx.x;
  const int per = 2*HW_;
  if (i >= 7*per) return;
  int f = i/per, r = i - f*per;
  float v; int slot;
  if (f < 4) { v = ff[f*per + r]; slot = f; }            // f01,f12,f23,f34 -> 0..3
  else       { v = fb[(f-4)*per + r]; slot = 10+(f-4); } // b10,b21,b32 -> 10..12
  flows[slot*per + r] = v;
}

// ------------------------------------------------------- bilinear (zero pad)
static __device__ __forceinline__ float bilin2(const float* __restrict__ img,
                                               float px, float py){
  float x0f = floorf(px), y0f = floorf(py);
  int x0 = (int)x0f, y0 = (int)y0f;
  float fx = px - x0f, fy = py - y0f;
  int x1 = x0+1, y1 = y0+1;
  bool vx0 = (x0>=0)&&(x0<W_), vx1 = (x1>=0)&&(x1<W_);
  bool vy0 = (y0>=0)&&(y0<H_), vy1 = (y1>=0)&&(y1<H_);
  float c00 = (vx0&&vy0)? img[y0*W_+x0] : 0.f;
  float c10 = (vx1&&vy0)? img[y0*W_+x1] : 0.f;
  float c01 = (vx0&&vy1)? img[y1*W_+x0] : 0.f;
  float c11 = (vx1&&vy1)? img[y1*W_+x1] : 0.f;
  return c00*(1.f-fx)*(1.f-fy) + c10*fx*(1.f-fy) + c01*(1.f-fx)*fy + c11*fx*fy;
}

// ------------------------------------------------------------- flow compose
struct Comps { int dst[5]; int a[5]; int src[5]; };

__global__ __launch_bounds__(256) void flow_compose_k(float* __restrict__ flows, Comps c){
  int ci  = blockIdx.y;
  int pix = blockIdx.x*256 + threadIdx.x;           // HW_ = 24*256
  float* D       = flows + c.dst[ci]*2*HW_;
  const float* A = flows + c.a[ci]  *2*HW_;
  const float* S = flows + c.src[ci]*2*HW_;
  float ax = A[pix], ay = A[HW_+pix];
  float px = (float)(pix % W_) + ax;
  float py = (float)(pix / W_) + ay;
  D[pix]      = ax + bilin2(S,      px, py);
  D[HW_+pix]  = ay + bilin2(S+HW_,  px, py);
}

// ------------------------------------------- weight f32 permute, co4 layout
// out[g][ci][k][j] = w[(g*4+j)][ci][k]   (g = co/4, j = co%4, k = 3x3 tap)
__global__ __launch_bounds__(256) void wcvt_k(const float* __restrict__ w,
                                              float* __restrict__ o,
                                              int Cin, int Cout){
  int idx = blockIdx.x*256 + threadIdx.x;
  if (idx >= Cout*Cin*9) return;
  int per = Cin*36;
  int g = idx / per, r = idx - g*per;
  int cik = r >> 2, j = r & 3;
  int ci = cik/9, k = cik - ci*9;
  o[idx] = w[(((g*4+j)*Cin)+ci)*9 + k];
}

// ------------------------------------------------------------- direct conv
// in: TIN [T][Cin][H][W].  OUTMODE 0: f32 channels-last [T*HW][Cout]
//                          OUTMODE 1: f32 channels-first [T][Cout][HW]
#define TAPFMA(TT, K) { float4 w = w4[K]; \
  a0 = fmaf(TT, w.x, a0); a1 = fmaf(TT, w.y, a1); \
  a2 = fmaf(TT, w.z, a2); a3 = fmaf(TT, w.w, a3); }

template<int OUTMODE, typename TIN>
__global__ __launch_bounds__(256) void conv3x3_k(const TIN* __restrict__ in,
                                                 const float* __restrict__ wf,
                                                 const float* __restrict__ bias,
                                                 void* __restrict__ outp,
                                                 int Cin, int Cout){
  int tile = blockIdx.x;                       // T * HW/256 = 120
  int t    = tile / (HW_/256);
  int pix  = (tile % (HW_/256))*256 + threadIdx.x;
  int y = pix / W_, x = pix - y*W_;
  int g = blockIdx.y;
  int co0 = g*4;
  bool xm = x>0, xp = x<(W_-1), ym = y>0, yp = y<(H_-1);
  const TIN* inb = in + (size_t)t*Cin*HW_ + pix;
  const float* wp = wf + (size_t)g*Cin*36;
  float a0=0.f, a1=0.f, a2=0.f, a3=0.f;
  for (int ci=0; ci<Cin; ++ci){
    const TIN* p = inb + ci*HW_;
    float t00 = (ym&&xm)? tof(p[-W_-1]) : 0.f;
    float t01 = ym      ? tof(p[-W_  ]) : 0.f;
    float t02 = (ym&&xp)? tof(p[-W_+1]) : 0.f;
    float t10 = xm      ? tof(p[-1])    : 0.f;
    float t11 =           tof(p[0]);
    float t12 = xp      ? tof(p[1])     : 0.f;
    float t20 = (yp&&xm)? tof(p[W_-1])  : 0.f;
    float t21 = yp      ? tof(p[W_  ])  : 0.f;
    float t22 = (yp&&xp)? tof(p[W_+1])  : 0.f;
    const float4* w4 = (const float4*)(wp + ci*36);
    TAPFMA(t00,0) TAPFMA(t01,1) TAPFMA(t02,2)
    TAPFMA(t10,3) TAPFMA(t11,4) TAPFMA(t12,5)
    TAPFMA(t20,6) TAPFMA(t21,7) TAPFMA(t22,8)
  }
  a0 += bias[co0+0]; a1 += bias[co0+1];
  a2 += bias[co0+2]; a3 += bias[co0+3];
  if (OUTMODE == 0){
    float4 r; r.x=a0; r.y=a1; r.z=a2; r.w=a3;
    *((float4*)((float*)outp + ((size_t)(t*HW_+pix)*Cout + co0))) = r;
  } else {
    float* o = (float*)outp;
    o[((size_t)t*Cout+co0+0)*HW_ + pix] = a0;
    o[((size_t)t*Cout+co0+1)*HW_ + pix] = a1;
    o[((size_t)t*Cout+co0+2)*HW_ + pix] = a2;
    o[((size_t)t*Cout+co0+3)*HW_ + pix] = a3;
  }
}

// ---------------------------------------------------------------- sampling
// flow-add slot per (t_q, l); -1 = zero.  Rows 3 and 4 identical per reference.
__device__ const int g_slotTab[25] = {
  -1,  0,  4,  5,  6,
  10, -1,  1,  7,  8,
  13, 11, -1,  2,  9,
  15, 14, 12, -1,  3,
  15, 14, 12, -1,  3 };

__global__ __launch_bounds__(256) void sample_k(const float* __restrict__ value,  // [T][HW][C] f32
                                                const float* __restrict__ off,    // [T*HW][320]
                                                const float* __restrict__ aw,     // [T*HW][160]
                                                const float* __restrict__ flows,  // [16][2][HW]
                                                const float* __restrict__ ref,    // [Lq][5][2]
                                                bf16* __restrict__ attn){         // [T][C][HW]
  __shared__ float lds[8*257];
  int u = threadIdx.x >> 5, d = threadIdx.x & 31;
  int q = blockIdx.x*8 + u;
  int t_q = q / HW_, pix = q - t_q*HW_;
  for (int h=0; h<NH_; ++h){
    const float* awp  = aw  + (size_t)q*160 + h*20;
    const float* offp = off + (size_t)q*320 + h*40;
    float e[20];
    float m = -1e30f;
    #pragma unroll
    for (int i=0;i<20;++i){ e[i]=awp[i]; m = fmaxf(m, e[i]); }
    float s=0.f;
    #pragma unroll
    for (int i=0;i<20;++i){ e[i]=__expf(e[i]-m); s+=e[i]; }
    float inv = 1.f/s;
    float acc = 0.f;
    #pragma unroll
    for (int l=0;l<NL_;++l){
      float rx = ref[(q*5+l)*2+0];
      float ry = ref[(q*5+l)*2+1];
      int slot = g_slotTab[t_q*5+l];
      float addx=0.f, addy=0.f;
      if (slot >= 0){ addx = flows[slot*2*HW_ + pix]; addy = flows[slot*2*HW_ + HW_ + pix]; }
      const float* vimg = value + (size_t)l*HW_*C_ + h*DH_ + d;
      float bx = rx*(float)W_ - 0.5f + addx;
      float by = ry*(float)H_ - 0.5f + addy;
      #pragma unroll
      for (int p=0;p<NP_;++p){
        float px = bx + offp[(l*4+p)*2+0];
        float py = by + offp[(l*4+p)*2+1];
        float x0f = floorf(px), y0f = floorf(py);
        float fx = px-x0f, fy = py-y0f;
        int x0=(int)x0f, y0=(int)y0f, x1=x0+1, y1=y0+1;
        bool vx0=(x0>=0)&&(x0<W_), vx1=(x1>=0)&&(x1<W_);
        bool vy0=(y0>=0)&&(y0<H_), vy1=(y1>=0)&&(y1<H_);
        float c00 = (vx0&&vy0)? vimg[(y0*W_+x0)*C_] : 0.f;
        float c10 = (vx1&&vy0)? vimg[(y0*W_+x1)*C_] : 0.f;
        float c01 = (vx0&&vy1)? vimg[(y1*W_+x0)*C_] : 0.f;
        float c11 = (vx1&&vy1)? vimg[(y1*W_+x1)*C_] : 0.f;
        float bl = c00*(1.f-fx)*(1.f-fy)+c10*fx*(1.f-fy)+c01*(1.f-fx)*fy+c11*fx*fy;
        acc = fmaf(e[l*4+p]*inv, bl, acc);
      }
    }
    lds[u*257 + h*32 + d] = acc;
  }
  __syncthreads();
  int t     = (blockIdx.x*8) / HW_;   // 8-aligned tiles never cross frames
  int pbase = (blockIdx.x*8) % HW_;
  for (int i=threadIdx.x; i<2048; i+=256){
    int c = i>>3, xo = i&7;
    attn[((size_t)t*C_ + c)*HW_ + pbase + xo] = __float2bfloat16(lds[xo*257 + c]);
  }
}

// ---------------------------------------------------------------- launcher
extern "C" void kernel_launch(void* const* d_in, const int* in_sizes, int n_in,
                              void* d_out, int out_size, void* d_ws, size_t ws_size,
                              hipStream_t stream) {
  const float* query   = (const float*)d_in[0];
  const float* in_flat = (const float*)d_in[1];
  const float* refpts  = (const float*)d_in[2];
  const float* ff      = (const float*)d_in[6];
  const float* fb      = (const float*)d_in[7];
  const float* w_off   = (const float*)d_in[8];
  const float* b_off   = (const float*)d_in[9];
  const float* w_attn  = (const float*)d_in[10];
  const float* b_attn  = (const float*)d_in[11];
  const float* w_val   = (const float*)d_in[12];
  const float* b_val   = (const float*)d_in[13];
  const float* w_out   = (const float*)d_in[14];
  const float* b_out   = (const float*)d_in[15];
  float* out = (float*)d_out;

  char* ws = (char*)d_ws;
  float* v_val   = (float*)(ws + 0);           // 31,457,280 B  [T*HW][256] f32
  float* v_off   = (float*)(ws + 31457280);    // 39,321,600 B  [T*HW][320] f32
  float* v_aw    = (float*)(ws + 70778880);    // 19,660,800 B  [T*HW][160] f32
  float* v_flows = (float*)(ws + 90439680);    //    786,432 B  [16][2][HW] f32
  bf16*  v_attn  = (bf16*) (ws + 91226112);    // 15,728,640 B  [T][256][HW] bf16
  float* wf_val  = (float*)(ws + 106954752);   //  2,359,296 B
  float* wf_off  = (float*)(ws + 109314048);   //  2,949,120 B
  float* wf_attn = (float*)(ws + 112263168);   //  1,474,560 B
  float* wf_out  = (float*)(ws + 113737728);   //  2,359,296 B -> end 116,097,024
  if (ws_size < (size_t)116097024) return;     // refuse to corrupt

  // weight permutation into [g][ci][k][co4] layout
  wcvt_k<<<(256*2304+255)/256, 256, 0, stream>>>(w_val,  wf_val,  256, 256);
  wcvt_k<<<(320*2304+255)/256, 256, 0, stream>>>(w_off,  wf_off,  256, 320);
  wcvt_k<<<(160*2304+255)/256, 256, 0, stream>>>(w_attn, wf_attn, 256, 160);
  wcvt_k<<<(256*2304+255)/256, 256, 0, stream>>>(w_out,  wf_out,  256, 256);

  // flows: init base fields, then 3 dependency stages of dst = a + warp(src, a)
  flow_init_k<<<(7*2*HW_+255)/256, 256, 0, stream>>>(ff, fb, v_flows);
  Comps A; // f02; f13; f24; b20; b31
  A.dst[0]=4;  A.a[0]=0;  A.src[0]=1;
  A.dst[1]=7;  A.a[1]=1;  A.src[1]=2;
  A.dst[2]=9;  A.a[2]=2;  A.src[2]=3;
  A.dst[3]=13; A.a[3]=11; A.src[3]=10;
  A.dst[4]=14; A.a[4]=12; A.src[4]=11;
  flow_compose_k<<<dim3(HW_/256,5), 256, 0, stream>>>(v_flows, A);
  Comps B; // f03; f14; b30
  B.dst[0]=5;  B.a[0]=4;  B.src[0]=2;
  B.dst[1]=8;  B.a[1]=7;  B.src[1]=3;
  B.dst[2]=15; B.a[2]=14; B.src[2]=10;
  B.dst[3]=0;  B.a[3]=0;  B.src[3]=0;
  B.dst[4]=0;  B.a[4]=0;  B.src[4]=0;
  flow_compose_k<<<dim3(HW_/256,3), 256, 0, stream>>>(v_flows, B);
  Comps Cc; // f04
  Cc.dst[0]=6; Cc.a[0]=5; Cc.src[0]=3;
  Cc.dst[1]=0; Cc.a[1]=0; Cc.src[1]=0;
  Cc.dst[2]=0; Cc.a[2]=0; Cc.src[2]=0;
  Cc.dst[3]=0; Cc.a[3]=0; Cc.src[3]=0;
  Cc.dst[4]=0; Cc.a[4]=0; Cc.src[4]=0;
  flow_compose_k<<<dim3(HW_/256,1), 256, 0, stream>>>(v_flows, Cc);

  // the three input convs (channels-last f32 outputs)
  conv3x3_k<0,float><<<dim3(T_*HW_/256, 64), 256, 0, stream>>>(in_flat, wf_val,  b_val,  v_val, 256, 256);
  conv3x3_k<0,float><<<dim3(T_*HW_/256, 80), 256, 0, stream>>>(query,   wf_off,  b_off,  v_off, 256, 320);
  conv3x3_k<0,float><<<dim3(T_*HW_/256, 40), 256, 0, stream>>>(query,   wf_attn, b_attn, v_aw,  256, 160);

  // deformable sampling + softmax + head recombine -> channels-first bf16
  sample_k<<<LQ_/8, 256, 0, stream>>>(v_val, v_off, v_aw, v_flows, refpts, v_attn);

  // output conv -> d_out (f32, channels-first)
  conv3x3_k<1,bf16><<<dim3(T_*HW_/256, 64), 256, 0, stream>>>(v_attn, wf_out, b_out, out, 256, 256);
}

// Round 4
// 2076.660 us; speedup vs baseline: 1.9666x; 1.9666x over previous
//
#include <hip/hip_runtime.h>
#include <hip/hip_bf16.h>

typedef __hip_bfloat16 bf16;
typedef __attribute__((ext_vector_type(8))) short short8;
typedef __attribute__((ext_vector_type(4))) float float4v;

#define T_  5
#define H_  64
#define W_  96
#define HW_ (H_*W_)
#define C_  256
#define NH_ 8
#define DH_ 32
#define NL_ 5
#define NP_ 4
#define LQ_ (T_*HW_)

// padded input geometry: [T][66][98][256] bf16
#define PH_ 66
#define PW_ 98
#define PADE_ (T_*PH_*PW_*C_)       // elements

static __device__ __forceinline__ void gl2lds16(const bf16* g, bf16* l){
  __builtin_amdgcn_global_load_lds(
      (const __attribute__((address_space(1))) unsigned int*)g,
      (__attribute__((address_space(3))) unsigned int*)l, 16, 0, 0);
}

// ---------------------------------------------------------------- zero fill
__global__ __launch_bounds__(256) void zfill_k(float4* __restrict__ p, int n4){
  int i = blockIdx.x*256 + threadIdx.x;
  if (i < n4){ float4 z; z.x=z.y=z.z=z.w=0.f; p[i]=z; }
}

// ------------------------------------------------- pad+cast+transpose input
// in f32 [T][256][HW] -> pad bf16 [T][66][98][256] (interior only)
__global__ __launch_bounds__(256) void pad_in_k(const float* __restrict__ in,
                                                bf16* __restrict__ pad){
  __shared__ bf16 sb[256][66];
  int t = blockIdx.y;
  int pix0 = blockIdx.x*64;
  int tid = threadIdx.x;
  int pl = tid & 63, cg = tid >> 6;
  #pragma unroll 4
  for (int it=0; it<64; ++it){
    int c = it*4 + cg;
    sb[c][pl] = __float2bfloat16(in[((size_t)t*C_ + c)*HW_ + pix0 + pl]);
  }
  __syncthreads();
  for (int p=0; p<64; ++p){
    int pix = pix0 + p;
    int y = pix/W_, x = pix - y*W_;
    pad[(((size_t)t*PH_ + y+1)*PW_ + x+1)*C_ + tid] = sb[tid][p];
  }
}

// ------------------------------------------------- weight permute to WT bf16
// WT[n][tap*256+ci] = w[n][ci][tap]
__global__ __launch_bounds__(256) void wt_k(const float* __restrict__ w,
                                            bf16* __restrict__ WT, int total){
  int idx = blockIdx.x*256 + threadIdx.x;
  if (idx >= total) return;
  int n = idx / 2304, r = idx - n*2304;
  int tap = r >> 8, ci = r & 255;
  WT[idx] = __float2bfloat16(w[((size_t)(n*C_+ci))*9 + tap]);
}

// combined off+attn weights: rows 0..319 w_off, 320..479 w_attn, 480..511 zero
__global__ __launch_bounds__(256) void wt_oa_k(const float* __restrict__ wo,
                                               const float* __restrict__ wa,
                                               bf16* __restrict__ WT){
  int idx = blockIdx.x*256 + threadIdx.x;
  if (idx >= 512*2304) return;
  int n = idx / 2304, r = idx - n*2304;
  int tap = r >> 8, ci = r & 255;
  float v = 0.f;
  if (n < 320)      v = wo[((size_t)(n*C_+ci))*9 + tap];
  else if (n < 480) v = wa[((size_t)((n-320)*C_+ci))*9 + tap];
  WT[idx] = __float2bfloat16(v);
}

__global__ __launch_bounds__(512) void bias_oa_k(const float* __restrict__ bo,
                                                 const float* __restrict__ ba,
                                                 float* __restrict__ b){
  int n = threadIdx.x;
  float v = 0.f;
  if (n < 320) v = bo[n]; else if (n < 480) v = ba[n-320];
  b[n] = v;
}

// ----------------------------------------------------------- implicit GEMM
// C[M=30720][N] = conv(Apad, WT) + bias.
// MODE 0: bf16 [M][256]   MODE 1: split f32 [M][320] / [M][160]   MODE 2: f32 [M][256]
#define BM 128
#define BN 128
#define BK 64

template<int MODE>
__global__ __launch_bounds__(256) void gemm_conv(const bf16* __restrict__ Apad,
                                                 const bf16* __restrict__ WT,
                                                 const float* __restrict__ bias,
                                                 void* __restrict__ out0,
                                                 void* __restrict__ out1){
  __shared__ __align__(16) bf16 As[BM*BK];   // [128 rows][8 slots][8 bf16], XOR-swizzled
  __shared__ __align__(16) bf16 Bs[BN*BK];
  int tid = threadIdx.x;
  int lane = tid & 63, wv = tid >> 6;
  int wm = wv & 1, wn = wv >> 1;
  int quad = lane >> 4, l15 = lane & 15;
  int bx = blockIdx.x, by = blockIdx.y;

  // staging thread constants: srow in 0..31, chunk c8 constant across j
  int srow = tid >> 3;
  int c8   = (tid & 7) ^ (srow & 7);
  long abase[4]; const bf16* brow[4];
  #pragma unroll
  for (int j=0;j<4;++j){
    int p = j*32 + srow;
    int P = bx*BM + p;
    int t = P / HW_, rem = P - t*HW_;
    int y = rem / W_, x = rem - y*W_;
    abase[j] = ((long)(t*PH_ + y)*PW_ + x)*C_ + c8*8;   // + ((dy*PW_+dx)*C_ + kc)
    brow[j]  = WT + (long)(by*BN + p)*2304 + c8*8;      // + (tap*256 + kc)
  }

  float4v acc[4][4];
  #pragma unroll
  for (int jn=0;jn<4;++jn){
    float bv = bias[by*BN + wn*64 + jn*16 + l15];
    #pragma unroll
    for (int i=0;i<4;++i){ acc[i][jn][0]=bv; acc[i][jn][1]=bv; acc[i][jn][2]=bv; acc[i][jn][3]=bv; }
  }

  for (int kt=0; kt<36; ++kt){
    int tap = kt >> 2, kc = (kt & 3) << 6;
    int dy = tap/3, dx = tap - dy*3;
    long ash = (long)(dy*PW_ + dx)*C_ + kc;
    long bsh = tap*256 + kc;
    __syncthreads();
    #pragma unroll
    for (int j=0;j<4;++j){
      gl2lds16(Apad + abase[j] + ash, As + (j*256+tid)*8);
      gl2lds16(brow[j] + bsh,         Bs + (j*256+tid)*8);
    }
    __syncthreads();
    #pragma unroll
    for (int kk=0; kk<2; ++kk){
      int slot = ((kk<<2) + quad) ^ (l15 & 7);
      short8 af[4], bfr[4];
      #pragma unroll
      for (int i=0;i<4;++i){
        af[i]  = *(const short8*)(As + (wm*64 + i*16 + l15)*BK + slot*8);
        bfr[i] = *(const short8*)(Bs + (wn*64 + i*16 + l15)*BK + slot*8);
      }
      #pragma unroll
      for (int i=0;i<4;++i)
        #pragma unroll
        for (int jn=0;jn<4;++jn)
          acc[i][jn] = __builtin_amdgcn_mfma_f32_16x16x32_bf16(af[i], bfr[jn], acc[i][jn], 0,0,0);
    }
  }

  #pragma unroll
  for (int i=0;i<4;++i){
    int mr = bx*BM + wm*64 + i*16 + quad*4;
    #pragma unroll
    for (int jn=0;jn<4;++jn){
      int nc = by*BN + wn*64 + jn*16 + l15;
      #pragma unroll
      for (int r=0;r<4;++r){
        float v = acc[i][jn][r];
        long m = mr + r;
        if (MODE == 0)      ((bf16*)out0)[m*256 + nc] = __float2bfloat16(v);
        else if (MODE == 2) ((float*)out0)[m*256 + nc] = v;
        else {
          if (nc < 320)      ((float*)out0)[m*320 + nc] = v;
          else if (nc < 480) ((float*)out1)[m*160 + nc - 320] = v;
        }
      }
    }
  }
}

// ------------------------------------------------------- bilinear (zero pad)
static __device__ __forceinline__ float bilin2(const float* __restrict__ img,
                                               float px, float py){
  float x0f = floorf(px), y0f = floorf(py);
  int x0 = (int)x0f, y0 = (int)y0f;
  float fx = px - x0f, fy = py - y0f;
  int x1 = x0+1, y1 = y0+1;
  bool vx0 = (x0>=0)&&(x0<W_), vx1 = (x1>=0)&&(x1<W_);
  bool vy0 = (y0>=0)&&(y0<H_), vy1 = (y1>=0)&&(y1<H_);
  float c00 = (vx0&&vy0)? img[y0*W_+x0] : 0.f;
  float c10 = (vx1&&vy0)? img[y0*W_+x1] : 0.f;
  float c01 = (vx0&&vy1)? img[y1*W_+x0] : 0.f;
  float c11 = (vx1&&vy1)? img[y1*W_+x1] : 0.f;
  return c00*(1.f-fx)*(1.f-fy) + c10*fx*(1.f-fy) + c01*(1.f-fx)*fy + c11*fx*fy;
}

// ---------------------------------------------------------------- flow init
__global__ __launch_bounds__(256) void flow_init_k(const float* __restrict__ ff,
                                                   const float* __restrict__ fb,
                                                   float* __restrict__ flows){
  int i = blockIdx.x*256 + threadIdx.x;
  const int per = 2*HW_;
  if (i >= 7*per) return;
  int f = i/per, r = i - f*per;
  float v; int slot;
  if (f < 4) { v = ff[f*per + r]; slot = f; }
  else       { v = fb[(f-4)*per + r]; slot = 10+(f-4); }
  flows[slot*per + r] = v;
}

// ------------------------------------------------------------- flow compose
struct Comps { int dst[5]; int a[5]; int src[5]; };

__global__ __launch_bounds__(256) void flow_compose_k(float* __restrict__ flows, Comps c){
  int ci  = blockIdx.y;
  int pix = blockIdx.x*256 + threadIdx.x;
  float* D       = flows + c.dst[ci]*2*HW_;
  const float* A = flows + c.a[ci]  *2*HW_;
  const float* S = flows + c.src[ci]*2*HW_;
  float ax = A[pix], ay = A[HW_+pix];
  float px = (float)(pix % W_) + ax;
  float py = (float)(pix / W_) + ay;
  D[pix]      = ax + bilin2(S,      px, py);
  D[HW_+pix]  = ay + bilin2(S+HW_,  px, py);
}

// ---------------------------------------------------------------- sampling
__device__ const int g_slotTab[25] = {
  -1,  0,  4,  5,  6,
  10, -1,  1,  7,  8,
  13, 11, -1,  2,  9,
  15, 14, 12, -1,  3,
  15, 14, 12, -1,  3 };

__global__ __launch_bounds__(256) void sample_k(const bf16*  __restrict__ value,  // [T*HW][256] bf16
                                                const float* __restrict__ off,    // [T*HW][320]
                                                const float* __restrict__ aw,     // [T*HW][160]
                                                const float* __restrict__ flows,  // [16][2][HW]
                                                const float* __restrict__ ref,    // [Lq][5][2]
                                                bf16* __restrict__ attn_pad){     // [T][66][98][256]
  int u = threadIdx.x >> 5, d = threadIdx.x & 31;
  int q = blockIdx.x*8 + u;
  int t_q = q / HW_, pix = q - t_q*HW_;
  int yq = pix / W_, xq = pix - yq*W_;
  bf16* dst = attn_pad + (((size_t)t_q*PH_ + yq+1)*PW_ + xq+1)*C_ + d;
  for (int h=0; h<NH_; ++h){
    const float* awp  = aw  + (size_t)q*160 + h*20;
    const float* offp = off + (size_t)q*320 + h*40;
    float e[20];
    float m = -1e30f;
    #pragma unroll
    for (int i=0;i<20;++i){ e[i]=awp[i]; m = fmaxf(m, e[i]); }
    float s=0.f;
    #pragma unroll
    for (int i=0;i<20;++i){ e[i]=__expf(e[i]-m); s+=e[i]; }
    float inv = 1.f/s;
    float acc = 0.f;
    #pragma unroll
    for (int l=0;l<NL_;++l){
      float rx = ref[(q*5+l)*2+0];
      float ry = ref[(q*5+l)*2+1];
      int slot = g_slotTab[t_q*5+l];
      float addx=0.f, addy=0.f;
      if (slot >= 0){ addx = flows[slot*2*HW_ + pix]; addy = flows[slot*2*HW_ + HW_ + pix]; }
      const bf16* vimg = value + (size_t)l*HW_*C_ + h*DH_ + d;
      float bx = rx*(float)W_ - 0.5f + addx;
      float by = ry*(float)H_ - 0.5f + addy;
      #pragma unroll
      for (int p=0;p<NP_;++p){
        float px = bx + offp[(l*4+p)*2+0];
        float py = by + offp[(l*4+p)*2+1];
        float x0f = floorf(px), y0f = floorf(py);
        float fx = px-x0f, fy = py-y0f;
        int x0=(int)x0f, y0=(int)y0f, x1=x0+1, y1=y0+1;
        bool vx0=(x0>=0)&&(x0<W_), vx1=(x1>=0)&&(x1<W_);
        bool vy0=(y0>=0)&&(y0<H_), vy1=(y1>=0)&&(y1<H_);
        float c00 = (vx0&&vy0)? __bfloat162float(vimg[(y0*W_+x0)*C_]) : 0.f;
        float c10 = (vx1&&vy0)? __bfloat162float(vimg[(y0*W_+x1)*C_]) : 0.f;
        float c01 = (vx0&&vy1)? __bfloat162float(vimg[(y1*W_+x0)*C_]) : 0.f;
        float c11 = (vx1&&vy1)? __bfloat162float(vimg[(y1*W_+x1)*C_]) : 0.f;
        float bl = c00*(1.f-fx)*(1.f-fy)+c10*fx*(1.f-fy)+c01*(1.f-fx)*fy+c11*fx*fy;
        acc = fmaf(e[l*4+p]*inv, bl, acc);
      }
    }
    dst[h*DH_] = __float2bfloat16(acc);
  }
}

// ------------------------------------------- C [M][256] f32 -> [T][256][HW]
__global__ __launch_bounds__(256) void out_tr_k(const float* __restrict__ Ccl,
                                                float* __restrict__ out){
  __shared__ float ob[32][257];
  int m0 = blockIdx.x*32;
  int tid = threadIdx.x;
  for (int it=0; it<32; ++it)
    ob[it][tid] = Ccl[(size_t)(m0+it)*256 + tid];
  __syncthreads();
  int t = m0 / HW_, pl = m0 - t*HW_;
  int p = tid & 31, cg = tid >> 5;
  for (int it=0; it<32; ++it){
    int c = it*8 + cg;
    out[((size_t)t*C_ + c)*HW_ + pl + p] = ob[p][c];
  }
}

// ---------------------------------------------------------------- launcher
extern "C" void kernel_launch(void* const* d_in, const int* in_sizes, int n_in,
                              void* d_out, int out_size, void* d_ws, size_t ws_size,
                              hipStream_t stream) {
  const float* query   = (const float*)d_in[0];
  const float* in_flat = (const float*)d_in[1];
  const float* refpts  = (const float*)d_in[2];
  const float* ff      = (const float*)d_in[6];
  const float* fb      = (const float*)d_in[7];
  const float* w_off   = (const float*)d_in[8];
  const float* b_off   = (const float*)d_in[9];
  const float* w_attn  = (const float*)d_in[10];
  const float* b_attn  = (const float*)d_in[11];
  const float* w_val   = (const float*)d_in[12];
  const float* b_val   = (const float*)d_in[13];
  const float* w_out   = (const float*)d_in[14];
  const float* b_out   = (const float*)d_in[15];
  float* out = (float*)d_out;

  char* ws = (char*)d_ws;
  bf16*  v_pad   = (bf16*) (ws + 0);           // 16,558,080 B  [T][66][98][256] bf16 (in_flat; later attn)
  bf16*  q_pad   = (bf16*) (ws + 16558080);    // 16,558,080 B  (query)
  bf16*  v_val   = (bf16*) (ws + 33116160);    // 15,728,640 B  [30720][256] bf16
  float* v_off   = (float*)(ws + 48844800);    // 39,321,600 B  [30720][320] f32 (later C_cl f32 [30720][256])
  float* v_aw    = (float*)(ws + 88166400);    // 19,660,800 B  [30720][160] f32
  float* v_flows = (float*)(ws + 107827200);   //    786,432 B
  bf16*  WT_val  = (bf16*) (ws + 108613632);   //  1,179,648 B  [256][2304]
  bf16*  WT_oa   = (bf16*) (ws + 109793280);   //  2,359,296 B  [512][2304]
  bf16*  WT_out  = (bf16*) (ws + 112152576);   //  1,179,648 B
  float* bias_oa = (float*)(ws + 113332224);   //      2,048 B -> end 113,334,272
  bf16*  attn_pad = v_pad;                      // alias (v_pad dead after val GEMM)
  float* C_cl     = v_off;                      // alias (v_off dead after sample_k)
  if (ws_size < (size_t)113334272) return;

  // zero both padded buffers (borders must be 0; single range covers both)
  zfill_k<<<(2069760+255)/256, 256, 0, stream>>>((float4*)ws, 2069760);

  // weights / bias
  wt_k<<<(256*2304+255)/256, 256, 0, stream>>>(w_val, WT_val, 256*2304);
  wt_oa_k<<<(512*2304+255)/256, 256, 0, stream>>>(w_off, w_attn, WT_oa);
  wt_k<<<(256*2304+255)/256, 256, 0, stream>>>(w_out, WT_out, 256*2304);
  bias_oa_k<<<1, 512, 0, stream>>>(b_off, b_attn, bias_oa);

  // flows
  flow_init_k<<<(7*2*HW_+255)/256, 256, 0, stream>>>(ff, fb, v_flows);
  Comps A;
  A.dst[0]=4;  A.a[0]=0;  A.src[0]=1;
  A.dst[1]=7;  A.a[1]=1;  A.src[1]=2;
  A.dst[2]=9;  A.a[2]=2;  A.src[2]=3;
  A.dst[3]=13; A.a[3]=11; A.src[3]=10;
  A.dst[4]=14; A.a[4]=12; A.src[4]=11;
  flow_compose_k<<<dim3(HW_/256,5), 256, 0, stream>>>(v_flows, A);
  Comps B;
  B.dst[0]=5;  B.a[0]=4;  B.src[0]=2;
  B.dst[1]=8;  B.a[1]=7;  B.src[1]=3;
  B.dst[2]=15; B.a[2]=14; B.src[2]=10;
  B.dst[3]=0;  B.a[3]=0;  B.src[3]=0;
  B.dst[4]=0;  B.a[4]=0;  B.src[4]=0;
  flow_compose_k<<<dim3(HW_/256,3), 256, 0, stream>>>(v_flows, B);
  Comps Cc;
  Cc.dst[0]=6; Cc.a[0]=5; Cc.src[0]=3;
  Cc.dst[1]=0; Cc.a[1]=0; Cc.src[1]=0;
  Cc.dst[2]=0; Cc.a[2]=0; Cc.src[2]=0;
  Cc.dst[3]=0; Cc.a[3]=0; Cc.src[3]=0;
  Cc.dst[4]=0; Cc.a[4]=0; Cc.src[4]=0;
  flow_compose_k<<<dim3(HW_/256,1), 256, 0, stream>>>(v_flows, Cc);

  // pad+cast inputs to channels-last bf16
  pad_in_k<<<dim3(HW_/64, T_), 256, 0, stream>>>(in_flat, v_pad);
  pad_in_k<<<dim3(HW_/64, T_), 256, 0, stream>>>(query,  q_pad);

  // convs as implicit GEMMs
  gemm_conv<0><<<dim3(240, 2), 256, 0, stream>>>(v_pad, WT_val, b_val,   v_val, nullptr);
  gemm_conv<1><<<dim3(240, 4), 256, 0, stream>>>(q_pad, WT_oa,  bias_oa, v_off, v_aw);

  // deformable sampling -> attn_pad (borders stay zero from zfill)
  sample_k<<<LQ_/8, 256, 0, stream>>>(v_val, v_off, v_aw, v_flows, refpts, attn_pad);

  // output conv -> channels-last f32, then transpose to NCHW
  gemm_conv<2><<<dim3(240, 2), 256, 0, stream>>>(attn_pad, WT_out, b_out, C_cl, nullptr);
  out_tr_k<<<LQ_/32, 256, 0, stream>>>(C_cl, out);
}

// Round 5
// 742.564 us; speedup vs baseline: 5.4998x; 2.7966x over previous
//
#include <hip/hip_runtime.h>
#include <hip/hip_bf16.h>

typedef __hip_bfloat16 bf16;
typedef __attribute__((ext_vector_type(8))) short short8;
typedef __attribute__((ext_vector_type(4))) float float4v;

#define T_  5
#define H_  64
#define W_  96
#define HW_ (H_*W_)
#define C_  256
#define NH_ 8
#define DH_ 32
#define NL_ 5
#define NP_ 4
#define LQ_ (T_*HW_)

// padded geometry: [T][66][98][256] bf16
#define PH_ 66
#define PW_ 98

static __device__ __forceinline__ void gl2lds16(const bf16* g, bf16* l){
  __builtin_amdgcn_global_load_lds(
      (const __attribute__((address_space(1))) unsigned int*)g,
      (__attribute__((address_space(3))) unsigned int*)l, 16, 0, 0);
}

// ---------------------------------------------------------------- zero fill
__global__ __launch_bounds__(256) void zfill_k(float4* __restrict__ p, int n4){
  int i = blockIdx.x*256 + threadIdx.x;
  if (i < n4){ float4 z; z.x=z.y=z.z=z.w=0.f; p[i]=z; }
}

// ------------------------------------------------- pad+cast+transpose input
__global__ __launch_bounds__(256) void pad_in_k(const float* __restrict__ in,
                                                bf16* __restrict__ pad){
  __shared__ bf16 sb[256][66];
  int t = blockIdx.y;
  int pix0 = blockIdx.x*64;
  int tid = threadIdx.x;
  int pl = tid & 63, cg = tid >> 6;
  #pragma unroll 4
  for (int it=0; it<64; ++it){
    int c = it*4 + cg;
    sb[c][pl] = __float2bfloat16(in[((size_t)t*C_ + c)*HW_ + pix0 + pl]);
  }
  __syncthreads();
  for (int p=0; p<64; ++p){
    int pix = pix0 + p;
    int y = pix/W_, x = pix - y*W_;
    pad[(((size_t)t*PH_ + y+1)*PW_ + x+1)*C_ + tid] = sb[tid][p];
  }
}

// ------------------------------------------------- weight permute to WT bf16
__global__ __launch_bounds__(256) void wt_k(const float* __restrict__ w,
                                            bf16* __restrict__ WT, int total){
  int idx = blockIdx.x*256 + threadIdx.x;
  if (idx >= total) return;
  int n = idx / 2304, r = idx - n*2304;
  int tap = r >> 8, ci = r & 255;
  WT[idx] = __float2bfloat16(w[((size_t)(n*C_+ci))*9 + tap]);
}

__global__ __launch_bounds__(256) void wt_oa_k(const float* __restrict__ wo,
                                               const float* __restrict__ wa,
                                               bf16* __restrict__ WT){
  int idx = blockIdx.x*256 + threadIdx.x;
  if (idx >= 512*2304) return;
  int n = idx / 2304, r = idx - n*2304;
  int tap = r >> 8, ci = r & 255;
  float v = 0.f;
  if (n < 320)      v = wo[((size_t)(n*C_+ci))*9 + tap];
  else if (n < 480) v = wa[((size_t)((n-320)*C_+ci))*9 + tap];
  WT[idx] = __float2bfloat16(v);
}

__global__ __launch_bounds__(512) void bias_oa_k(const float* __restrict__ bo,
                                                 const float* __restrict__ ba,
                                                 float* __restrict__ b){
  int n = threadIdx.x;
  float v = 0.f;
  if (n < 320) v = bo[n]; else if (n < 480) v = ba[n-320];
  b[n] = v;
}

// ----------------------------------------------------------- implicit GEMM
#define BM 128
#define BN 128
#define BK 64

template<int MODE>
__global__ __launch_bounds__(256) void gemm_conv(const bf16* __restrict__ Apad,
                                                 const bf16* __restrict__ WT,
                                                 const float* __restrict__ bias,
                                                 void* __restrict__ out0,
                                                 void* __restrict__ out1){
  __shared__ __align__(16) bf16 As[BM*BK];
  __shared__ __align__(16) bf16 Bs[BN*BK];
  int tid = threadIdx.x;
  int lane = tid & 63, wv = tid >> 6;
  int wm = wv & 1, wn = wv >> 1;
  int quad = lane >> 4, l15 = lane & 15;
  int bx = blockIdx.x, by = blockIdx.y;

  int srow = tid >> 3;
  int c8   = (tid & 7) ^ (srow & 7);
  long abase[4]; const bf16* brow[4];
  #pragma unroll
  for (int j=0;j<4;++j){
    int p = j*32 + srow;
    int P = bx*BM + p;
    int t = P / HW_, rem = P - t*HW_;
    int y = rem / W_, x = rem - y*W_;
    abase[j] = ((long)(t*PH_ + y)*PW_ + x)*C_ + c8*8;
    brow[j]  = WT + (long)(by*BN + p)*2304 + c8*8;
  }

  float4v acc[4][4];
  #pragma unroll
  for (int jn=0;jn<4;++jn){
    float bv = bias[by*BN + wn*64 + jn*16 + l15];
    #pragma unroll
    for (int i=0;i<4;++i){ acc[i][jn][0]=bv; acc[i][jn][1]=bv; acc[i][jn][2]=bv; acc[i][jn][3]=bv; }
  }

  for (int kt=0; kt<36; ++kt){
    int tap = kt >> 2, kc = (kt & 3) << 6;
    int dy = tap/3, dx = tap - dy*3;
    long ash = (long)(dy*PW_ + dx)*C_ + kc;
    long bsh = tap*256 + kc;
    __syncthreads();
    #pragma unroll
    for (int j=0;j<4;++j){
      gl2lds16(Apad + abase[j] + ash, As + (j*256+tid)*8);
      gl2lds16(brow[j] + bsh,         Bs + (j*256+tid)*8);
    }
    __syncthreads();
    #pragma unroll
    for (int kk=0; kk<2; ++kk){
      int slot = ((kk<<2) + quad) ^ (l15 & 7);
      short8 af[4], bfr[4];
      #pragma unroll
      for (int i=0;i<4;++i){
        af[i]  = *(const short8*)(As + (wm*64 + i*16 + l15)*BK + slot*8);
        bfr[i] = *(const short8*)(Bs + (wn*64 + i*16 + l15)*BK + slot*8);
      }
      #pragma unroll
      for (int i=0;i<4;++i)
        #pragma unroll
        for (int jn=0;jn<4;++jn)
          acc[i][jn] = __builtin_amdgcn_mfma_f32_16x16x32_bf16(af[i], bfr[jn], acc[i][jn], 0,0,0);
    }
  }

  #pragma unroll
  for (int i=0;i<4;++i){
    int mr = bx*BM + wm*64 + i*16 + quad*4;
    #pragma unroll
    for (int jn=0;jn<4;++jn){
      int nc = by*BN + wn*64 + jn*16 + l15;
      #pragma unroll
      for (int r=0;r<4;++r){
        float v = acc[i][jn][r];
        long m = mr + r;
        if (MODE == 0)      ((bf16*)out0)[m*256 + nc] = __float2bfloat16(v);
        else if (MODE == 2) ((float*)out0)[m*256 + nc] = v;
        else {
          if (nc < 320)      ((float*)out0)[m*320 + nc] = v;
          else if (nc < 480) ((float*)out1)[m*160 + nc - 320] = v;
        }
      }
    }
  }
}

// ------------------------------------------------------- bilinear (zero pad)
static __device__ __forceinline__ float bilin2(const float* __restrict__ img,
                                               float px, float py){
  float x0f = floorf(px), y0f = floorf(py);
  int x0 = (int)x0f, y0 = (int)y0f;
  float fx = px - x0f, fy = py - y0f;
  int x1 = x0+1, y1 = y0+1;
  bool vx0 = (x0>=0)&&(x0<W_), vx1 = (x1>=0)&&(x1<W_);
  bool vy0 = (y0>=0)&&(y0<H_), vy1 = (y1>=0)&&(y1<H_);
  float c00 = (vx0&&vy0)? img[y0*W_+x0] : 0.f;
  float c10 = (vx1&&vy0)? img[y0*W_+x1] : 0.f;
  float c01 = (vx0&&vy1)? img[y1*W_+x0] : 0.f;
  float c11 = (vx1&&vy1)? img[y1*W_+x1] : 0.f;
  return c00*(1.f-fx)*(1.f-fy) + c10*fx*(1.f-fy) + c01*(1.f-fx)*fy + c11*fx*fy;
}

// ---------------------------------------------------------------- flow init
__global__ __launch_bounds__(256) void flow_init_k(const float* __restrict__ ff,
                                                   const float* __restrict__ fb,
                                                   float* __restrict__ flows){
  int i = blockIdx.x*256 + threadIdx.x;
  const int per = 2*HW_;
  if (i >= 7*per) return;
  int f = i/per, r = i - f*per;
  float v; int slot;
  if (f < 4) { v = ff[f*per + r]; slot = f; }
  else       { v = fb[(f-4)*per + r]; slot = 10+(f-4); }
  flows[slot*per + r] = v;
}

// ------------------------------------------------------------- flow compose
struct Comps { int dst[5]; int a[5]; int src[5]; };

__global__ __launch_bounds__(256) void flow_compose_k(float* __restrict__ flows, Comps c){
  int ci  = blockIdx.y;
  int pix = blockIdx.x*256 + threadIdx.x;
  float* D       = flows + c.dst[ci]*2*HW_;
  const float* A = flows + c.a[ci]  *2*HW_;
  const float* S = flows + c.src[ci]*2*HW_;
  float ax = A[pix], ay = A[HW_+pix];
  float px = (float)(pix % W_) + ax;
  float py = (float)(pix / W_) + ay;
  D[pix]      = ax + bilin2(S,      px, py);
  D[HW_+pix]  = ay + bilin2(S+HW_,  px, py);
}

// ---------------------------------------------------------------- prep
__device__ const int g_slotTab[25] = {
  -1,  0,  4,  5,  6,
  10, -1,  1,  7,  8,
  13, 11, -1,  2,  9,
  15, 14, 12, -1,  3,
  15, 14, 12, -1,  3 };

// per (q,l): base = ref*[W,H] - 0.5 + flow_add
__global__ __launch_bounds__(256) void bases_k(const float* __restrict__ ref,
                                               const float* __restrict__ flows,
                                               float* __restrict__ bases){
  int i = blockIdx.x*256 + threadIdx.x;       // q*5+l, 153600 total
  int q = i/5, l = i - q*5;
  int t_q = q / HW_, pix = q - t_q*HW_;
  int slot = g_slotTab[t_q*5+l];
  float ax=0.f, ay=0.f;
  if (slot >= 0){ ax = flows[slot*2*HW_ + pix]; ay = flows[slot*2*HW_ + HW_ + pix]; }
  bases[i*2+0] = ref[i*2+0]*(float)W_ - 0.5f + ax;
  bases[i*2+1] = ref[i*2+1]*(float)H_ - 0.5f + ay;
}

// in-place softmax over 20, one (q,h) per thread
__global__ __launch_bounds__(256) void softmax20_k(float* __restrict__ aw){
  int unit = blockIdx.x*256 + threadIdx.x;    // 245760 total
  float4* p4 = (float4*)(aw + (size_t)unit*20);
  float4 v[5];
  #pragma unroll
  for (int i=0;i<5;++i) v[i] = p4[i];
  float* e = (float*)v;
  float m = -1e30f;
  #pragma unroll
  for (int i=0;i<20;++i) m = fmaxf(m, e[i]);
  float s = 0.f;
  #pragma unroll
  for (int i=0;i<20;++i){ e[i] = __expf(e[i]-m); s += e[i]; }
  float inv = 1.f/s;
  #pragma unroll
  for (int i=0;i<20;++i) e[i] *= inv;
  #pragma unroll
  for (int i=0;i<5;++i) p4[i] = v[i];
}

// ---------------------------------------------------------------- sampling
// thread = (q, h, channel-pair e). 16-lane group per (q,h); uint loads (2 bf16).
__global__ __launch_bounds__(256) void sample_k(const bf16*  __restrict__ value,  // [T][HW][256] bf16
                                                const float* __restrict__ off,    // [T*HW][320]
                                                const float* __restrict__ awn,    // [T*HW][160] normalized
                                                const float* __restrict__ bases,  // [T*HW][5][2]
                                                bf16* __restrict__ attn_pad){     // [T][66][98][256]
  int tid = threadIdx.x;
  int g = tid >> 4, e = tid & 15;
  int unit = blockIdx.x*16 + g;               // 0..245759
  int q = unit >> 3, h = unit & 7;
  int t_q = q / HW_, pix = q - t_q*HW_;
  int yq = pix / W_, xq = pix - yq*W_;

  const float* bp   = bases + (size_t)q*10;
  const float* offp = off   + (size_t)q*320 + h*40;
  const float* ap   = awn   + (size_t)q*160 + h*20;

  float acc0 = 0.f, acc1 = 0.f;
  #pragma unroll
  for (int l=0; l<NL_; ++l){
    float bx = bp[l*2+0], by = bp[l*2+1];
    const unsigned* vimg = (const unsigned*)(value + ((size_t)l*HW_)*C_ + h*DH_ + e*2);
    #pragma unroll
    for (int p=0; p<NP_; ++p){
      float px = bx + offp[(l*4+p)*2+0];
      float py = by + offp[(l*4+p)*2+1];
      float wgt = ap[l*4+p];
      float x0f = floorf(px), y0f = floorf(py);
      float fx = px-x0f, fy = py-y0f;
      int x0=(int)x0f, y0=(int)y0f, x1=x0+1, y1=y0+1;
      bool vx0=(x0>=0)&&(x0<W_), vx1=(x1>=0)&&(x1<W_);
      bool vy0=(y0>=0)&&(y0<H_), vy1=(y1>=0)&&(y1<H_);
      unsigned u00 = (vx0&&vy0)? vimg[(size_t)(y0*W_+x0)*128] : 0u;   // *C_/2 uints
      unsigned u10 = (vx1&&vy0)? vimg[(size_t)(y0*W_+x1)*128] : 0u;
      unsigned u01 = (vx0&&vy1)? vimg[(size_t)(y1*W_+x0)*128] : 0u;
      unsigned u11 = (vx1&&vy1)? vimg[(size_t)(y1*W_+x1)*128] : 0u;
      float w00 = wgt*(1.f-fx)*(1.f-fy), w10 = wgt*fx*(1.f-fy);
      float w01 = wgt*(1.f-fx)*fy,       w11 = wgt*fx*fy;
      union {unsigned v; float f;} a, b;
      a.v = u00<<16;          acc0 = fmaf(w00, a.f, acc0);
      b.v = u00 & 0xffff0000u; acc1 = fmaf(w00, b.f, acc1);
      a.v = u10<<16;          acc0 = fmaf(w10, a.f, acc0);
      b.v = u10 & 0xffff0000u; acc1 = fmaf(w10, b.f, acc1);
      a.v = u01<<16;          acc0 = fmaf(w01, a.f, acc0);
      b.v = u01 & 0xffff0000u; acc1 = fmaf(w01, b.f, acc1);
      a.v = u11<<16;          acc0 = fmaf(w11, a.f, acc0);
      b.v = u11 & 0xffff0000u; acc1 = fmaf(w11, b.f, acc1);
    }
  }
  union {unsigned u; bf16 hh[2];} pk;
  pk.hh[0] = __float2bfloat16(acc0);
  pk.hh[1] = __float2bfloat16(acc1);
  *(unsigned*)(attn_pad + (((size_t)t_q*PH_ + yq+1)*PW_ + xq+1)*C_ + h*DH_ + e*2) = pk.u;
}

// ------------------------------------------- C [M][256] f32 -> [T][256][HW]
__global__ __launch_bounds__(256) void out_tr_k(const float* __restrict__ Ccl,
                                                float* __restrict__ out){
  __shared__ float ob[32][257];
  int m0 = blockIdx.x*32;
  int tid = threadIdx.x;
  for (int it=0; it<32; ++it)
    ob[it][tid] = Ccl[(size_t)(m0+it)*256 + tid];
  __syncthreads();
  int t = m0 / HW_, pl = m0 - t*HW_;
  int p = tid & 31, cg = tid >> 5;
  for (int it=0; it<32; ++it){
    int c = it*8 + cg;
    out[((size_t)t*C_ + c)*HW_ + pl + p] = ob[p][c];
  }
}

// ---------------------------------------------------------------- launcher
extern "C" void kernel_launch(void* const* d_in, const int* in_sizes, int n_in,
                              void* d_out, int out_size, void* d_ws, size_t ws_size,
                              hipStream_t stream) {
  const float* query   = (const float*)d_in[0];
  const float* in_flat = (const float*)d_in[1];
  const float* refpts  = (const float*)d_in[2];
  const float* ff      = (const float*)d_in[6];
  const float* fb      = (const float*)d_in[7];
  const float* w_off   = (const float*)d_in[8];
  const float* b_off   = (const float*)d_in[9];
  const float* w_attn  = (const float*)d_in[10];
  const float* b_attn  = (const float*)d_in[11];
  const float* w_val   = (const float*)d_in[12];
  const float* b_val   = (const float*)d_in[13];
  const float* w_out   = (const float*)d_in[14];
  const float* b_out   = (const float*)d_in[15];
  float* out = (float*)d_out;

  char* ws = (char*)d_ws;
  bf16*  v_pad   = (bf16*) (ws + 0);           // 16,558,080 B (in_flat; later attn)
  bf16*  q_pad   = (bf16*) (ws + 16558080);    // 16,558,080 B
  bf16*  v_val   = (bf16*) (ws + 33116160);    // 15,728,640 B
  float* v_off   = (float*)(ws + 48844800);    // 39,321,600 B (later C_cl f32)
  float* v_aw    = (float*)(ws + 88166400);    // 19,660,800 B
  float* v_flows = (float*)(ws + 107827200);   //    786,432 B
  bf16*  WT_val  = (bf16*) (ws + 108613632);   //  1,179,648 B
  bf16*  WT_oa   = (bf16*) (ws + 109793280);   //  2,359,296 B
  bf16*  WT_out  = (bf16*) (ws + 112152576);   //  1,179,648 B
  float* bias_oa = (float*)(ws + 113332224);   //      2,048 B
  float* v_bases = (float*)(ws + 113334272);   //  1,228,800 B -> end 114,563,072
  bf16*  attn_pad = v_pad;
  float* C_cl     = v_off;
  if (ws_size < (size_t)114563072) return;

  zfill_k<<<(2069760+255)/256, 256, 0, stream>>>((float4*)ws, 2069760);

  wt_k<<<(256*2304+255)/256, 256, 0, stream>>>(w_val, WT_val, 256*2304);
  wt_oa_k<<<(512*2304+255)/256, 256, 0, stream>>>(w_off, w_attn, WT_oa);
  wt_k<<<(256*2304+255)/256, 256, 0, stream>>>(w_out, WT_out, 256*2304);
  bias_oa_k<<<1, 512, 0, stream>>>(b_off, b_attn, bias_oa);

  flow_init_k<<<(7*2*HW_+255)/256, 256, 0, stream>>>(ff, fb, v_flows);
  Comps A;
  A.dst[0]=4;  A.a[0]=0;  A.src[0]=1;
  A.dst[1]=7;  A.a[1]=1;  A.src[1]=2;
  A.dst[2]=9;  A.a[2]=2;  A.src[2]=3;
  A.dst[3]=13; A.a[3]=11; A.src[3]=10;
  A.dst[4]=14; A.a[4]=12; A.src[4]=11;
  flow_compose_k<<<dim3(HW_/256,5), 256, 0, stream>>>(v_flows, A);
  Comps B;
  B.dst[0]=5;  B.a[0]=4;  B.src[0]=2;
  B.dst[1]=8;  B.a[1]=7;  B.src[1]=3;
  B.dst[2]=15; B.a[2]=14; B.src[2]=10;
  B.dst[3]=0;  B.a[3]=0;  B.src[3]=0;
  B.dst[4]=0;  B.a[4]=0;  B.src[4]=0;
  flow_compose_k<<<dim3(HW_/256,3), 256, 0, stream>>>(v_flows, B);
  Comps Cc;
  Cc.dst[0]=6; Cc.a[0]=5; Cc.src[0]=3;
  Cc.dst[1]=0; Cc.a[1]=0; Cc.src[1]=0;
  Cc.dst[2]=0; Cc.a[2]=0; Cc.src[2]=0;
  Cc.dst[3]=0; Cc.a[3]=0; Cc.src[3]=0;
  Cc.dst[4]=0; Cc.a[4]=0; Cc.src[4]=0;
  flow_compose_k<<<dim3(HW_/256,1), 256, 0, stream>>>(v_flows, Cc);

  pad_in_k<<<dim3(HW_/64, T_), 256, 0, stream>>>(in_flat, v_pad);
  pad_in_k<<<dim3(HW_/64, T_), 256, 0, stream>>>(query,  q_pad);

  gemm_conv<0><<<dim3(240, 2), 256, 0, stream>>>(v_pad, WT_val, b_val,   v_val, nullptr);
  gemm_conv<1><<<dim3(240, 4), 256, 0, stream>>>(q_pad, WT_oa,  bias_oa, v_off, v_aw);

  // prep: bases + softmax-normalized weights
  bases_k<<<(LQ_*5)/256, 256, 0, stream>>>(refpts, v_flows, v_bases);
  softmax20_k<<<(LQ_*NH_)/256, 256, 0, stream>>>(v_aw);

  // deformable sampling (borders of attn_pad stay zero from zfill)
  sample_k<<<(LQ_*NH_)/16, 256, 0, stream>>>(v_val, v_off, v_aw, v_bases, attn_pad);

  gemm_conv<2><<<dim3(240, 2), 256, 0, stream>>>(attn_pad, WT_out, b_out, C_cl, nullptr);
  out_tr_k<<<LQ_/32, 256, 0, stream>>>(C_cl, out);
}

// Round 6
// 535.623 us; speedup vs baseline: 7.6246x; 1.3864x over previous
//
#include <hip/hip_runtime.h>
#include <hip/hip_bf16.h>
#include <hip/hip_fp16.h>

typedef __hip_bfloat16 bf16;
typedef __attribute__((ext_vector_type(8))) short short8;
typedef __attribute__((ext_vector_type(4))) float float4v;

#define T_  5
#define H_  64
#define W_  96
#define HW_ (H_*W_)
#define C_  256
#define NH_ 8
#define DH_ 32
#define NL_ 5
#define NP_ 4
#define LQ_ (T_*HW_)
#define UNITS_ (LQ_*NH_)          // 245760

// padded geometry: [T][66][98][256] bf16
#define PH_ 66
#define PW_ 98

static __device__ __forceinline__ void gl2lds16(const bf16* g, bf16* l){
  __builtin_amdgcn_global_load_lds(
      (const __attribute__((address_space(1))) unsigned int*)g,
      (__attribute__((address_space(3))) unsigned int*)l, 16, 0, 0);
}

// ---------------------------------------------------------------- zero fill
__global__ __launch_bounds__(256) void zfill_k(float4* __restrict__ p, int n4){
  int i = blockIdx.x*256 + threadIdx.x;
  if (i < n4){ float4 z; z.x=z.y=z.z=z.w=0.f; p[i]=z; }
}

// ------------------------------------------------- pad+cast+transpose input
__global__ __launch_bounds__(256) void pad_in_k(const float* __restrict__ in,
                                                bf16* __restrict__ pad){
  __shared__ bf16 sb[256][66];
  int t = blockIdx.y;
  int pix0 = blockIdx.x*64;
  int tid = threadIdx.x;
  int pl = tid & 63, cg = tid >> 6;
  #pragma unroll 4
  for (int it=0; it<64; ++it){
    int c = it*4 + cg;
    sb[c][pl] = __float2bfloat16(in[((size_t)t*C_ + c)*HW_ + pix0 + pl]);
  }
  __syncthreads();
  for (int p=0; p<64; ++p){
    int pix = pix0 + p;
    int y = pix/W_, x = pix - y*W_;
    pad[(((size_t)t*PH_ + y+1)*PW_ + x+1)*C_ + tid] = sb[tid][p];
  }
}

// ------------------------------------------------- weight permute to WT bf16
__global__ __launch_bounds__(256) void wt_k(const float* __restrict__ w,
                                            bf16* __restrict__ WT, int total){
  int idx = blockIdx.x*256 + threadIdx.x;
  if (idx >= total) return;
  int n = idx / 2304, r = idx - n*2304;
  int tap = r >> 8, ci = r & 255;
  WT[idx] = __float2bfloat16(w[((size_t)(n*C_+ci))*9 + tap]);
}

__global__ __launch_bounds__(256) void wt_oa_k(const float* __restrict__ wo,
                                               const float* __restrict__ wa,
                                               bf16* __restrict__ WT){
  int idx = blockIdx.x*256 + threadIdx.x;
  if (idx >= 512*2304) return;
  int n = idx / 2304, r = idx - n*2304;
  int tap = r >> 8, ci = r & 255;
  float v = 0.f;
  if (n < 320)      v = wo[((size_t)(n*C_+ci))*9 + tap];
  else if (n < 480) v = wa[((size_t)((n-320)*C_+ci))*9 + tap];
  WT[idx] = __float2bfloat16(v);
}

__global__ __launch_bounds__(512) void bias_oa_k(const float* __restrict__ bo,
                                                 const float* __restrict__ ba,
                                                 float* __restrict__ b){
  int n = threadIdx.x;
  float v = 0.f;
  if (n < 320) v = bo[n]; else if (n < 480) v = ba[n-320];
  b[n] = v;
}

// ----------------------------------------------------------- implicit GEMM
#define BM 128
#define BN 128
#define BK 64

// MODE 0: bf16 [M][256]   MODE 1: off scatter [l][unit][4][2] f32 + aw [unit][20] f32
// MODE 2: f32 [M][256]
template<int MODE>
__global__ __launch_bounds__(256) void gemm_conv(const bf16* __restrict__ Apad,
                                                 const bf16* __restrict__ WT,
                                                 const float* __restrict__ bias,
                                                 void* __restrict__ out0,
                                                 void* __restrict__ out1){
  __shared__ __align__(16) bf16 As[BM*BK];
  __shared__ __align__(16) bf16 Bs[BN*BK];
  int tid = threadIdx.x;
  int lane = tid & 63, wv = tid >> 6;
  int wm = wv & 1, wn = wv >> 1;
  int quad = lane >> 4, l15 = lane & 15;
  int bx = blockIdx.x, by = blockIdx.y;

  int srow = tid >> 3;
  int c8   = (tid & 7) ^ (srow & 7);
  long abase[4]; const bf16* brow[4];
  #pragma unroll
  for (int j=0;j<4;++j){
    int p = j*32 + srow;
    int P = bx*BM + p;
    int t = P / HW_, rem = P - t*HW_;
    int y = rem / W_, x = rem - y*W_;
    abase[j] = ((long)(t*PH_ + y)*PW_ + x)*C_ + c8*8;
    brow[j]  = WT + (long)(by*BN + p)*2304 + c8*8;
  }

  float4v acc[4][4];
  #pragma unroll
  for (int jn=0;jn<4;++jn){
    float bv = bias[by*BN + wn*64 + jn*16 + l15];
    #pragma unroll
    for (int i=0;i<4;++i){ acc[i][jn][0]=bv; acc[i][jn][1]=bv; acc[i][jn][2]=bv; acc[i][jn][3]=bv; }
  }

  for (int kt=0; kt<36; ++kt){
    int tap = kt >> 2, kc = (kt & 3) << 6;
    int dy = tap/3, dx = tap - dy*3;
    long ash = (long)(dy*PW_ + dx)*C_ + kc;
    long bsh = tap*256 + kc;
    __syncthreads();
    #pragma unroll
    for (int j=0;j<4;++j){
      gl2lds16(Apad + abase[j] + ash, As + (j*256+tid)*8);
      gl2lds16(brow[j] + bsh,         Bs + (j*256+tid)*8);
    }
    __syncthreads();
    #pragma unroll
    for (int kk=0; kk<2; ++kk){
      int slot = ((kk<<2) + quad) ^ (l15 & 7);
      short8 af[4], bfr[4];
      #pragma unroll
      for (int i=0;i<4;++i){
        af[i]  = *(const short8*)(As + (wm*64 + i*16 + l15)*BK + slot*8);
        bfr[i] = *(const short8*)(Bs + (wn*64 + i*16 + l15)*BK + slot*8);
      }
      #pragma unroll
      for (int i=0;i<4;++i)
        #pragma unroll
        for (int jn=0;jn<4;++jn)
          acc[i][jn] = __builtin_amdgcn_mfma_f32_16x16x32_bf16(af[i], bfr[jn], acc[i][jn], 0,0,0);
    }
  }

  #pragma unroll
  for (int i=0;i<4;++i){
    int mr = bx*BM + wm*64 + i*16 + quad*4;
    #pragma unroll
    for (int jn=0;jn<4;++jn){
      int nc = by*BN + wn*64 + jn*16 + l15;
      #pragma unroll
      for (int r=0;r<4;++r){
        float v = acc[i][jn][r];
        long m = mr + r;
        if (MODE == 0)      ((bf16*)out0)[m*256 + nc] = __float2bfloat16(v);
        else if (MODE == 2) ((float*)out0)[m*256 + nc] = v;
        else {
          if (nc < 320){
            int h = nc/40, rr = nc - h*40;
            int l = rr >> 3, pxy = rr & 7;
            ((float*)out0)[((size_t)l*UNITS_ + m*8 + h)*8 + pxy] = v;
          } else if (nc < 480){
            int hh = (nc-320)/20, ii = (nc-320) - hh*20;
            ((float*)out1)[((size_t)m*8 + hh)*20 + ii] = v;
          }
        }
      }
    }
  }
}

// ------------------------------------------------------- bilinear (zero pad)
static __device__ __forceinline__ float bilin2(const float* __restrict__ img,
                                               float px, float py){
  float x0f = floorf(px), y0f = floorf(py);
  int x0 = (int)x0f, y0 = (int)y0f;
  float fx = px - x0f, fy = py - y0f;
  int x1 = x0+1, y1 = y0+1;
  bool vx0 = (x0>=0)&&(x0<W_), vx1 = (x1>=0)&&(x1<W_);
  bool vy0 = (y0>=0)&&(y0<H_), vy1 = (y1>=0)&&(y1<H_);
  float c00 = (vx0&&vy0)? img[y0*W_+x0] : 0.f;
  float c10 = (vx1&&vy0)? img[y0*W_+x1] : 0.f;
  float c01 = (vx0&&vy1)? img[y1*W_+x0] : 0.f;
  float c11 = (vx1&&vy1)? img[y1*W_+x1] : 0.f;
  return c00*(1.f-fx)*(1.f-fy) + c10*fx*(1.f-fy) + c01*(1.f-fx)*fy + c11*fx*fy;
}

// ---------------------------------------------------------------- flow init
__global__ __launch_bounds__(256) void flow_init_k(const float* __restrict__ ff,
                                                   const float* __restrict__ fb,
                                                   float* __restrict__ flows){
  int i = blockIdx.x*256 + threadIdx.x;
  const int per = 2*HW_;
  if (i >= 7*per) return;
  int f = i/per, r = i - f*per;
  float v; int slot;
  if (f < 4) { v = ff[f*per + r]; slot = f; }
  else       { v = fb[(f-4)*per + r]; slot = 10+(f-4); }
  flows[slot*per + r] = v;
}

// ------------------------------------------------------------- flow compose
struct Comps { int dst[5]; int a[5]; int src[5]; };

__global__ __launch_bounds__(256) void flow_compose_k(float* __restrict__ flows, Comps c){
  int ci  = blockIdx.y;
  int pix = blockIdx.x*256 + threadIdx.x;
  float* D       = flows + c.dst[ci]*2*HW_;
  const float* A = flows + c.a[ci]  *2*HW_;
  const float* S = flows + c.src[ci]*2*HW_;
  float ax = A[pix], ay = A[HW_+pix];
  float px = (float)(pix % W_) + ax;
  float py = (float)(pix / W_) + ay;
  D[pix]      = ax + bilin2(S,      px, py);
  D[HW_+pix]  = ay + bilin2(S+HW_,  px, py);
}

// ---------------------------------------------------------------- prep
__device__ const int g_slotTab[25] = {
  -1,  0,  4,  5,  6,
  10, -1,  1,  7,  8,
  13, 11, -1,  2,  9,
  15, 14, 12, -1,  3,
  15, 14, 12, -1,  3 };

// fold base (ref*WH - 0.5 + flow_add) into P in place.  i = l*UNITS + unit
__global__ __launch_bounds__(256) void fold_k(const float* __restrict__ ref,
                                              const float* __restrict__ flows,
                                              float* __restrict__ P){
  int i = blockIdx.x*256 + threadIdx.x;   // 1,228,800 total
  int l = i / UNITS_, unit = i - l*UNITS_;
  int q = unit >> 3;
  int t_q = q / HW_, pix = q - t_q*HW_;
  int slot = g_slotTab[t_q*5+l];
  float ax=0.f, ay=0.f;
  if (slot >= 0){ ax = flows[slot*2*HW_ + pix]; ay = flows[slot*2*HW_ + HW_ + pix]; }
  float bx = ref[(q*5+l)*2+0]*(float)W_ - 0.5f + ax;
  float by = ref[(q*5+l)*2+1]*(float)H_ - 0.5f + ay;
  float2* pp = (float2*)(P + (size_t)i*8);
  #pragma unroll
  for (int p=0;p<4;++p){ float2 v = pp[p]; v.x += bx; v.y += by; pp[p] = v; }
}

// softmax over 20 (one (q,h) per thread), f32 in -> f16 normalized out
__global__ __launch_bounds__(256) void softmax20h_k(const float* __restrict__ aw,
                                                    __half* __restrict__ w16){
  int unit = blockIdx.x*256 + threadIdx.x;    // 245760 total
  const float4* p4 = (const float4*)(aw + (size_t)unit*20);
  float4 v[5];
  #pragma unroll
  for (int i=0;i<5;++i) v[i] = p4[i];
  float* e = (float*)v;
  float m = -1e30f;
  #pragma unroll
  for (int i=0;i<20;++i) m = fmaxf(m, e[i]);
  float s = 0.f;
  #pragma unroll
  for (int i=0;i<20;++i){ e[i] = __expf(e[i]-m); s += e[i]; }
  float inv = 1.f/s;
  __half2* o2 = (__half2*)(w16 + (size_t)unit*20);
  #pragma unroll
  for (int i=0;i<10;++i)
    o2[i] = __floats2half2_rn(e[2*i]*inv, e[2*i+1]*inv);
}

// ------------------------------------------------------- per-level sampling
// thread = (group g, lane e); group handles one (q,h), 16 lanes = 32 channels.
template<bool FIRST, bool LAST>
__global__ __launch_bounds__(256) void phase_k(const unsigned* __restrict__ vimg0, // value slice l, uint view
                                               const float2*  __restrict__ Pl,    // P + l*UNITS*4 (float2/point)
                                               const __half*  __restrict__ wl,    // w16 + l*4, stride 20
                                               float2* __restrict__ acc,          // [UNITS*16]
                                               bf16* __restrict__ attn_pad){
  __shared__ float4 sW[16][4];
  __shared__ int4   sI[16][4];
  int tid = threadIdx.x;
  if (tid < 64){
    int g = tid >> 2, p = tid & 3;
    int unit = blockIdx.x*16 + g;
    float2 pp = Pl[(size_t)unit*4 + p];
    float w = __half2float(wl[(size_t)unit*20 + p]);
    float x0f = floorf(pp.x), y0f = floorf(pp.y);
    float fx = pp.x - x0f,    fy = pp.y - y0f;
    int x0 = (int)x0f, y0 = (int)y0f;
    int x1 = x0+1, y1 = y0+1;
    float wx0 = 1.f-fx, wx1 = fx, wy0 = 1.f-fy, wy1 = fy;
    if ((unsigned)x0 >= (unsigned)W_) wx0 = 0.f;
    if ((unsigned)x1 >= (unsigned)W_) wx1 = 0.f;
    if ((unsigned)y0 >= (unsigned)H_) wy0 = 0.f;
    if ((unsigned)y1 >= (unsigned)H_) wy1 = 0.f;
    int xc0 = min(max(x0,0),W_-1), xc1 = min(max(x1,0),W_-1);
    int yc0 = min(max(y0,0),H_-1), yc1 = min(max(y1,0),H_-1);
    sW[g][p] = make_float4(w*wx0*wy0, w*wx1*wy0, w*wx0*wy1, w*wx1*wy1);
    sI[g][p] = make_int4((yc0*W_+xc0)*128, (yc0*W_+xc1)*128,
                         (yc1*W_+xc0)*128, (yc1*W_+xc1)*128);
  }
  __syncthreads();
  int g = tid >> 4, e = tid & 15;
  int unit = blockIdx.x*16 + g;
  int q = unit >> 3, h = unit & 7;
  const unsigned* vimg = vimg0 + h*16 + e;
  float a0, a1;
  if (FIRST){ a0 = 0.f; a1 = 0.f; }
  else { float2 c = acc[(size_t)unit*16 + e]; a0 = c.x; a1 = c.y; }
  #pragma unroll
  for (int p=0; p<4; ++p){
    float4 w4 = sW[g][p];
    int4   i4 = sI[g][p];
    unsigned u00 = vimg[i4.x], u10 = vimg[i4.y];
    unsigned u01 = vimg[i4.z], u11 = vimg[i4.w];
    union {unsigned v; float f;} lo, hi;
    lo.v = u00<<16; hi.v = u00 & 0xffff0000u;
    a0 = fmaf(w4.x, lo.f, a0); a1 = fmaf(w4.x, hi.f, a1);
    lo.v = u10<<16; hi.v = u10 & 0xffff0000u;
    a0 = fmaf(w4.y, lo.f, a0); a1 = fmaf(w4.y, hi.f, a1);
    lo.v = u01<<16; hi.v = u01 & 0xffff0000u;
    a0 = fmaf(w4.z, lo.f, a0); a1 = fmaf(w4.z, hi.f, a1);
    lo.v = u11<<16; hi.v = u11 & 0xffff0000u;
    a0 = fmaf(w4.w, lo.f, a0); a1 = fmaf(w4.w, hi.f, a1);
  }
  if (LAST){
    int t_q = q / HW_, pix = q - t_q*HW_;
    int yq = pix / W_, xq = pix - yq*W_;
    union {unsigned u; bf16 hh[2];} pk;
    pk.hh[0] = __float2bfloat16(a0);
    pk.hh[1] = __float2bfloat16(a1);
    *(unsigned*)(attn_pad + (((size_t)t_q*PH_ + yq+1)*PW_ + xq+1)*C_ + h*DH_ + e*2) = pk.u;
  } else {
    acc[(size_t)unit*16 + e] = make_float2(a0, a1);
  }
}

// ------------------------------------------- C [M][256] f32 -> [T][256][HW]
__global__ __launch_bounds__(256) void out_tr_k(const float* __restrict__ Ccl,
                                                float* __restrict__ out){
  __shared__ float ob[32][257];
  int m0 = blockIdx.x*32;
  int tid = threadIdx.x;
  for (int it=0; it<32; ++it)
    ob[it][tid] = Ccl[(size_t)(m0+it)*256 + tid];
  __syncthreads();
  int t = m0 / HW_, pl = m0 - t*HW_;
  int p = tid & 31, cg = tid >> 5;
  for (int it=0; it<32; ++it){
    int c = it*8 + cg;
    out[((size_t)t*C_ + c)*HW_ + pl + p] = ob[p][c];
  }
}

// ---------------------------------------------------------------- launcher
extern "C" void kernel_launch(void* const* d_in, const int* in_sizes, int n_in,
                              void* d_out, int out_size, void* d_ws, size_t ws_size,
                              hipStream_t stream) {
  const float* query   = (const float*)d_in[0];
  const float* in_flat = (const float*)d_in[1];
  const float* refpts  = (const float*)d_in[2];
  const float* ff      = (const float*)d_in[6];
  const float* fb      = (const float*)d_in[7];
  const float* w_off   = (const float*)d_in[8];
  const float* b_off   = (const float*)d_in[9];
  const float* w_attn  = (const float*)d_in[10];
  const float* b_attn  = (const float*)d_in[11];
  const float* w_val   = (const float*)d_in[12];
  const float* b_val   = (const float*)d_in[13];
  const float* w_out   = (const float*)d_in[14];
  const float* b_out   = (const float*)d_in[15];
  float* out = (float*)d_out;

  // ---- memory map (peak 114,075,648 B; proven budget >= 116,097,024) ----
  char* ws = (char*)d_ws;
  bf16*  v_pad   = (bf16*) (ws + 0);            // 16,558,080  in_flat pad -> attn_pad
  bf16*  v_val   = (bf16*) (ws + 16558080);     // 15,728,640  [5][HW][256] gather source
  float* P       = (float*)(ws + 32286720);     // 39,321,600  [5][UNITS][4][2] f32
  // pool @71,608,320 (41,287,680 B):
  bf16*  q_pad   = (bf16*) (ws + 71608320);     // 16,558,080  (early)
  float* v_aw    = (float*)(ws + 88166400);     // 19,660,800  (early)
  bf16*  WT_val  = (bf16*) (ws + 107827200);    //  1,179,648  (early)
  bf16*  WT_oa   = (bf16*) (ws + 109006848);    //  2,359,296  (early)
  float* v_flows = (float*)(ws + 111366144);    //    786,432  (early)
  float* bias_oa = (float*)(ws + 112152576);    //      2,048  (early)
  __half* w16    = (__half*)(ws + 71608320);    //  9,830,400  (late, over dead q_pad)
  float2* acc    = (float2*)(ws + 81438720);    // 31,457,280  (late, over dead v_aw/WTs/flows)
  float* C_cl    = (float*) (ws + 81438720);    // alias acc (after phases)
  bf16*  WT_out  = (bf16*) (ws + 112896000);    //  1,179,648  -> end 114,075,648
  bf16*  attn_pad = v_pad;
  if (ws_size < (size_t)114075648) return;

  // zero both padded buffers (borders must be 0)
  zfill_k<<<(1034880+255)/256, 256, 0, stream>>>((float4*)v_pad, 1034880);
  zfill_k<<<(1034880+255)/256, 256, 0, stream>>>((float4*)q_pad, 1034880);

  // weights / bias
  wt_k<<<(256*2304+255)/256, 256, 0, stream>>>(w_val, WT_val, 256*2304);
  wt_oa_k<<<(512*2304+255)/256, 256, 0, stream>>>(w_off, w_attn, WT_oa);
  wt_k<<<(256*2304+255)/256, 256, 0, stream>>>(w_out, WT_out, 256*2304);
  bias_oa_k<<<1, 512, 0, stream>>>(b_off, b_attn, bias_oa);

  // flows
  flow_init_k<<<(7*2*HW_+255)/256, 256, 0, stream>>>(ff, fb, v_flows);
  Comps A;
  A.dst[0]=4;  A.a[0]=0;  A.src[0]=1;
  A.dst[1]=7;  A.a[1]=1;  A.src[1]=2;
  A.dst[2]=9;  A.a[2]=2;  A.src[2]=3;
  A.dst[3]=13; A.a[3]=11; A.src[3]=10;
  A.dst[4]=14; A.a[4]=12; A.src[4]=11;
  flow_compose_k<<<dim3(HW_/256,5), 256, 0, stream>>>(v_flows, A);
  Comps B;
  B.dst[0]=5;  B.a[0]=4;  B.src[0]=2;
  B.dst[1]=8;  B.a[1]=7;  B.src[1]=3;
  B.dst[2]=15; B.a[2]=14; B.src[2]=10;
  B.dst[3]=0;  B.a[3]=0;  B.src[3]=0;
  B.dst[4]=0;  B.a[4]=0;  B.src[4]=0;
  flow_compose_k<<<dim3(HW_/256,3), 256, 0, stream>>>(v_flows, B);
  Comps Cc;
  Cc.dst[0]=6; Cc.a[0]=5; Cc.src[0]=3;
  Cc.dst[1]=0; Cc.a[1]=0; Cc.src[1]=0;
  Cc.dst[2]=0; Cc.a[2]=0; Cc.src[2]=0;
  Cc.dst[3]=0; Cc.a[3]=0; Cc.src[3]=0;
  Cc.dst[4]=0; Cc.a[4]=0; Cc.src[4]=0;
  flow_compose_k<<<dim3(HW_/256,1), 256, 0, stream>>>(v_flows, Cc);

  // pad+cast inputs
  pad_in_k<<<dim3(HW_/64, T_), 256, 0, stream>>>(in_flat, v_pad);
  pad_in_k<<<dim3(HW_/64, T_), 256, 0, stream>>>(query,  q_pad);

  // convs as implicit GEMMs
  gemm_conv<0><<<dim3(240, 2), 256, 0, stream>>>(v_pad, WT_val, b_val,   v_val, nullptr);
  gemm_conv<1><<<dim3(240, 4), 256, 0, stream>>>(q_pad, WT_oa,  bias_oa, P,     v_aw);

  // fold bases into P (in place); normalize aw -> f16
  fold_k<<<(NL_*UNITS_)/256, 256, 0, stream>>>(refpts, v_flows, P);
  softmax20h_k<<<UNITS_/256, 256, 0, stream>>>(v_aw, w16);

  // per-level sampling phases (L2-resident gather slices)
  {
    const unsigned* vb = (const unsigned*)v_val;
    phase_k<true ,false><<<UNITS_/16, 256, 0, stream>>>(vb + 0ul*HW_*128,
        (const float2*)(P + 0ul*UNITS_*8), w16 + 0, acc, attn_pad);
    phase_k<false,false><<<UNITS_/16, 256, 0, stream>>>(vb + 1ul*HW_*128,
        (const float2*)(P + 1ul*UNITS_*8), w16 + 4, acc, attn_pad);
    phase_k<false,false><<<UNITS_/16, 256, 0, stream>>>(vb + 2ul*HW_*128,
        (const float2*)(P + 2ul*UNITS_*8), w16 + 8, acc, attn_pad);
    phase_k<false,false><<<UNITS_/16, 256, 0, stream>>>(vb + 3ul*HW_*128,
        (const float2*)(P + 3ul*UNITS_*8), w16 + 12, acc, attn_pad);
    phase_k<false,true ><<<UNITS_/16, 256, 0, stream>>>(vb + 4ul*HW_*128,
        (const float2*)(P + 4ul*UNITS_*8), w16 + 16, acc, attn_pad);
  }

  // output conv -> channels-last f32, then transpose to NCHW
  gemm_conv<2><<<dim3(240, 2), 256, 0, stream>>>(attn_pad, WT_out, b_out, C_cl, nullptr);
  out_tr_k<<<LQ_/32, 256, 0, stream>>>(C_cl, out);
}